// Round 1
// baseline (1197.094 us; speedup 1.0000x reference)
//
#include <hip/hip_runtime.h>
#include <hip/hip_bf16.h>
#include <stdint.h>

#define B_ 32
#define T_ 2048
#define H_ 1024
#define M_ (B_*T_)

typedef __bf16 bf16x8 __attribute__((ext_vector_type(8)));
typedef float  f32x4  __attribute__((ext_vector_type(4)));

__device__ __forceinline__ float tanh_fast(float x) {
    // tanh(x) = 1 - 2/(e^{2x}+1); saturates correctly for |x| large
    float e = __expf(2.0f * x);
    return 1.0f - 2.0f / (e + 1.0f);
}

// ---------------- K0a: dec_p[b,o] = sum_k dec[b,k] * W_dec[o,k] (fp32) ----------------
// grid 512 = (b 32) x (oc 16); 4 threads per output o, each does a 256-wide k quarter.
__global__ __launch_bounds__(256) void k_decp(const float* __restrict__ dec,
                                              const float* __restrict__ Wd,
                                              float* __restrict__ decp) {
    int bx = blockIdx.x;
    int b = bx & 31, oc = bx >> 5;
    int tid = threadIdx.x;
    int o = oc * 64 + (tid >> 2);
    int kq = tid & 3;
    const f32x4* wr = (const f32x4*)&Wd[(size_t)o * H_ + kq * 256];
    const f32x4* dr = (const f32x4*)&dec[(size_t)b * H_ + kq * 256];
    f32x4 s4 = {0.f, 0.f, 0.f, 0.f};
#pragma unroll 8
    for (int i = 0; i < 64; ++i) s4 += wr[i] * dr[i];
    float s = s4[0] + s4[1] + s4[2] + s4[3];
    s += __shfl_xor(s, 1);
    s += __shfl_xor(s, 2);
    if (kq == 0) decp[b * H_ + o] = s;
}

// ---------------- K0b: tile W_enc fp32 -> bf16 fragment-major ----------------
// cell index tg = (kc*64 + ng)*64 + lane ; cell holds W[o=ng*16+(lane&15)][k=kc*32+(lane>>4)*8 .. +8]
__global__ __launch_bounds__(256) void k_wtile(const float* __restrict__ We,
                                               __bf16* __restrict__ Wt) {
    int tg = blockIdx.x * 256 + threadIdx.x;   // 0..131071 (grid 512)
    int kc = tg >> 12;
    int ng = (tg >> 6) & 63;
    int lane = tg & 63;
    int rr = lane & 15, qq = lane >> 4;
    int o = ng * 16 + rr;
    int k = kc * 32 + qq * 8;
    const f32x4* src = (const f32x4*)&We[(size_t)o * H_ + k];
    f32x4 f0 = src[0], f1 = src[1];
    bf16x8 h;
    h[0] = (__bf16)f0[0]; h[1] = (__bf16)f0[1]; h[2] = (__bf16)f0[2]; h[3] = (__bf16)f0[3];
    h[4] = (__bf16)f1[0]; h[5] = (__bf16)f1[1]; h[6] = (__bf16)f1[2]; h[7] = (__bf16)f1[3];
    *(bf16x8*)&Wt[(size_t)tg * 8] = h;
}

// ---------------- K1: fused GEMM + tanh + dot(v) -> scores ----------------
// One block = 64 (b,t) rows. A (64x1024) resident in LDS as bf16 fragment-major.
// Waves: 4; per n-tile (256 cols), wave w owns cols [nt*256+w*64, +64) = 4x4 MFMA 16x16x32 tiles.
// B-fragments read directly from pre-tiled global W (L2-hot) -> no barriers in k-loop.
__global__ __launch_bounds__(256, 1) void k_scores(const float* __restrict__ enc,
                                                   const float* __restrict__ decp,
                                                   const __bf16* __restrict__ Wt,
                                                   const float* __restrict__ v,
                                                   float* __restrict__ scores) {
    __shared__ __bf16 A_lds[64 * 1024];   // 128 KB, fragment-major: cell=((kc*4+mg)*64+lane)*8
    __shared__ float red[4][64];          // cross-wave score reduction

    const int tid = threadIdx.x;
    const int w = tid >> 6, lane = tid & 63;
    const int r = lane & 15, quad = lane >> 4;
    const int m0 = blockIdx.x * 64;
    const int b = m0 >> 11;               // m0 / 2048

    // ---- stage A: rows m0..m0+63, fp32 -> bf16, fragment-major ----
    {
        const int row_off = tid >> 7;     // 0..1 (two rows per iteration)
        const int tt = tid & 127;         // covers k = tt*8 .. +8
        const int kc = tt >> 2;
        const int lq = tt & 3;
#pragma unroll 4
        for (int i2 = 0; i2 < 32; ++i2) {
            int row = i2 * 2 + row_off;
            int mg = row >> 4, rr = row & 15;
            const f32x4* src = (const f32x4*)&enc[(size_t)(m0 + row) * H_ + tt * 8];
            f32x4 f0 = src[0], f1 = src[1];
            bf16x8 h;
            h[0] = (__bf16)f0[0]; h[1] = (__bf16)f0[1]; h[2] = (__bf16)f0[2]; h[3] = (__bf16)f0[3];
            h[4] = (__bf16)f1[0]; h[5] = (__bf16)f1[1]; h[6] = (__bf16)f1[2]; h[7] = (__bf16)f1[3];
            int cell = (kc * 4 + mg) * 64 + (lq * 16 + rr);
            *(bf16x8*)&A_lds[cell * 8] = h;
        }
    }
    __syncthreads();

    float sp[4][4] = {};   // per-lane partial scores: row = i*16 + quad*4 + g

#pragma unroll 1
    for (int nt = 0; nt < 4; ++nt) {
        const int nb = nt * 256 + w * 64;     // wave's column base
        const int ngbase = nt * 16 + w * 4;   // W fragment group base

        float dp[4], vvv[4];
#pragma unroll
        for (int j = 0; j < 4; ++j) {
            int col = nb + j * 16 + r;
            dp[j]  = decp[b * H_ + col];
            vvv[j] = v[col];
        }

        f32x4 acc[4][4];
#pragma unroll
        for (int i = 0; i < 4; ++i)
#pragma unroll
            for (int j = 0; j < 4; ++j) {
                f32x4 z; z[0] = dp[j]; z[1] = dp[j]; z[2] = dp[j]; z[3] = dp[j];
                acc[i][j] = z;   // dec_p folded into the accumulator init
            }

        bf16x8 a_cur[4], b_cur[4], a_nxt[4], b_nxt[4];
#pragma unroll
        for (int i = 0; i < 4; ++i)
            a_cur[i] = *(const bf16x8*)&A_lds[((0 * 4 + i) * 64 + lane) * 8];
#pragma unroll
        for (int j = 0; j < 4; ++j)
            b_cur[j] = *(const bf16x8*)&Wt[((size_t)(0 * 64 + ngbase + j) * 64 + lane) * 8];

#pragma unroll
        for (int ks = 0; ks < 32; ++ks) {
            if (ks < 31) {
#pragma unroll
                for (int j = 0; j < 4; ++j)
                    b_nxt[j] = *(const bf16x8*)&Wt[((size_t)((ks + 1) * 64 + ngbase + j) * 64 + lane) * 8];
#pragma unroll
                for (int i = 0; i < 4; ++i)
                    a_nxt[i] = *(const bf16x8*)&A_lds[(((ks + 1) * 4 + i) * 64 + lane) * 8];
            }
#pragma unroll
            for (int i = 0; i < 4; ++i)
#pragma unroll
                for (int j = 0; j < 4; ++j)
                    acc[i][j] = __builtin_amdgcn_mfma_f32_16x16x32_bf16(a_cur[i], b_cur[j], acc[i][j], 0, 0, 0);
            if (ks < 31) {
#pragma unroll
                for (int i = 0; i < 4; ++i) a_cur[i] = a_nxt[i];
#pragma unroll
                for (int j = 0; j < 4; ++j) b_cur[j] = b_nxt[j];
            }
        }

        // epilogue: sp[row] += sum_j tanh(C + dec_p) * v[col]
#pragma unroll
        for (int i = 0; i < 4; ++i)
#pragma unroll
            for (int j = 0; j < 4; ++j)
#pragma unroll
                for (int g = 0; g < 4; ++g)
                    sp[i][g] += tanh_fast(acc[i][j][g]) * vvv[j];
    }

    // reduce over the 16 column-lanes (lane bits 0..3)
#pragma unroll
    for (int i = 0; i < 4; ++i)
#pragma unroll
        for (int g = 0; g < 4; ++g) {
            float s = sp[i][g];
            s += __shfl_xor(s, 1);
            s += __shfl_xor(s, 2);
            s += __shfl_xor(s, 4);
            s += __shfl_xor(s, 8);
            sp[i][g] = s;
        }

    if (r == 0) {
#pragma unroll
        for (int i = 0; i < 4; ++i)
#pragma unroll
            for (int g = 0; g < 4; ++g)
                red[w][i * 16 + quad * 4 + g] = sp[i][g];
    }
    __syncthreads();
    if (tid < 64) {
        float s = red[0][tid] + red[1][tid] + red[2][tid] + red[3][tid];
        scores[m0 + tid] = s;
    }
}

// ---------------- K2: masked softmax over T per batch row ----------------
__global__ __launch_bounds__(256) void k_softmax(const float* __restrict__ scores,
                                                 const int* __restrict__ mask,
                                                 float* __restrict__ attn) {
    int b = blockIdx.x;
    int tid = threadIdx.x;
    int w = tid >> 6, lane = tid & 63;
    __shared__ float sm[2][4];
    float val[8];
    float mx = -3e38f;
#pragma unroll
    for (int ii = 0; ii < 8; ++ii) {
        int t = tid + ii * 256;
        float s = scores[b * T_ + t];
        s = (mask[b * T_ + t] == 0) ? -1e9f : s;
        val[ii] = s;
        mx = fmaxf(mx, s);
    }
#pragma unroll
    for (int m = 1; m <= 32; m <<= 1) mx = fmaxf(mx, __shfl_xor(mx, m));
    if (lane == 0) sm[0][w] = mx;
    __syncthreads();
    mx = fmaxf(fmaxf(sm[0][0], sm[0][1]), fmaxf(sm[0][2], sm[0][3]));
    float lsum = 0.f;
#pragma unroll
    for (int ii = 0; ii < 8; ++ii) {
        val[ii] = __expf(val[ii] - mx);
        lsum += val[ii];
    }
#pragma unroll
    for (int m = 1; m <= 32; m <<= 1) lsum += __shfl_xor(lsum, m);
    if (lane == 0) sm[1][w] = lsum;
    __syncthreads();
    float inv = 1.0f / (sm[1][0] + sm[1][1] + sm[1][2] + sm[1][3]);
#pragma unroll
    for (int ii = 0; ii < 8; ++ii)
        attn[b * T_ + tid + ii * 256] = val[ii] * inv;
}

// ---------------- K3: context[b,h] = sum_t attn[b,t] * enc[b,t,h] ----------------
// grid 512 = (b 32) x (hc 4: 256-wide h chunk) x (tq 4: 512-wide t chunk); atomics combine tq.
__global__ __launch_bounds__(256) void k_context(const float* __restrict__ enc,
                                                 const float* __restrict__ attn,
                                                 float* __restrict__ ctx) {
    int bx = blockIdx.x;
    int b = bx >> 4;
    int sub = bx & 15;
    int hc = sub & 3;
    int tq = sub >> 2;
    int tid = threadIdx.x;
    int wv = tid >> 6, lane = tid & 63;
    int h4 = hc * 256 + lane * 4;
    int t0 = tq * 512 + wv * 128;
    f32x4 acc = {0.f, 0.f, 0.f, 0.f};
#pragma unroll 4
    for (int i = 0; i < 128; ++i) {
        int t = t0 + i;
        float a = attn[b * T_ + t];
        f32x4 e = *(const f32x4*)&enc[((size_t)(b * T_ + t)) * H_ + h4];
        acc += a * e;
    }
    float* out = &ctx[b * H_ + h4];
    atomicAdd(&out[0], acc[0]);
    atomicAdd(&out[1], acc[1]);
    atomicAdd(&out[2], acc[2]);
    atomicAdd(&out[3], acc[3]);
}

extern "C" void kernel_launch(void* const* d_in, const int* in_sizes, int n_in,
                              void* d_out, int out_size, void* d_ws, size_t ws_size,
                              hipStream_t stream) {
    (void)in_sizes; (void)n_in; (void)out_size; (void)ws_size;
    const float* dec  = (const float*)d_in[0];
    const float* enc  = (const float*)d_in[1];
    const int*   mask = (const int*)d_in[2];
    const float* We   = (const float*)d_in[3];
    const float* Wd   = (const float*)d_in[4];
    const float* v    = (const float*)d_in[5];

    float* out = (float*)d_out;                 // [0,32768) context ; [32768,98304) attn
    char* ws = (char*)d_ws;
    float*  decp   = (float*)ws;                        // 32768 f32  (128 KB)
    float*  scores = (float*)(ws + 131072);             // 65536 f32  (256 KB)
    __bf16* Wt     = (__bf16*)(ws + 131072 + 262144);   // 1M bf16    (2 MB)

    // zero the context region (accumulated via atomics)
    hipMemsetAsync(out, 0, (size_t)B_ * H_ * sizeof(float), stream);

    k_decp   <<<512, 256, 0, stream>>>(dec, Wd, decp);
    k_wtile  <<<512, 256, 0, stream>>>(We, Wt);
    k_scores <<<1024, 256, 0, stream>>>(enc, decp, Wt, v, scores);
    k_softmax<<<32, 256, 0, stream>>>(scores, mask, out + B_ * H_);
    k_context<<<512, 256, 0, stream>>>(enc, out + B_ * H_, out);
}

// Round 2
// 595.576 us; speedup vs baseline: 2.0100x; 2.0100x over previous
//
#include <hip/hip_runtime.h>
#include <hip/hip_bf16.h>
#include <stdint.h>

#define B_ 32
#define T_ 2048
#define H_ 1024
#define M_ (B_*T_)

typedef __bf16 bf16x8 __attribute__((ext_vector_type(8)));
typedef float  f32x4  __attribute__((ext_vector_type(4)));

__device__ __forceinline__ float tanh_fast(float x) {
    float e = __expf(2.0f * x);
    return 1.0f - 2.0f / (e + 1.0f);
}

// ---------------- K0a: dec_p[b,o] = sum_k dec[b,k] * W_dec[o,k] (fp32) ----------------
__global__ __launch_bounds__(256) void k_decp(const float* __restrict__ dec,
                                              const float* __restrict__ Wd,
                                              float* __restrict__ decp) {
    int bx = blockIdx.x;
    int b = bx & 31, oc = bx >> 5;
    int tid = threadIdx.x;
    int o = oc * 64 + (tid >> 2);
    int kq = tid & 3;
    const f32x4* wr = (const f32x4*)&Wd[(size_t)o * H_ + kq * 256];
    const f32x4* dr = (const f32x4*)&dec[(size_t)b * H_ + kq * 256];
    f32x4 s4 = {0.f, 0.f, 0.f, 0.f};
#pragma unroll 8
    for (int i = 0; i < 64; ++i) s4 += wr[i] * dr[i];
    float s = s4[0] + s4[1] + s4[2] + s4[3];
    s += __shfl_xor(s, 1);
    s += __shfl_xor(s, 2);
    if (kq == 0) decp[b * H_ + o] = s;
}

// ---------------- K0b: tile W_enc fp32 -> bf16 fragment-major ----------------
// cell tg = (kk*64 + ng)*64 + lane ; holds W[o=ng*16+(lane&15)][k=kk*32+(lane>>4)*8 .. +8]
__global__ __launch_bounds__(256) void k_wtile(const float* __restrict__ We,
                                               __bf16* __restrict__ Wt) {
    int tg = blockIdx.x * 256 + threadIdx.x;   // grid 512 -> 131072 cells
    int kk = tg >> 12;
    int ng = (tg >> 6) & 63;
    int lane = tg & 63;
    int rr = lane & 15, qq = lane >> 4;
    int o = ng * 16 + rr;
    int k = kk * 32 + qq * 8;
    const f32x4* src = (const f32x4*)&We[(size_t)o * H_ + k];
    f32x4 f0 = src[0], f1 = src[1];
    bf16x8 h;
    h[0] = (__bf16)f0[0]; h[1] = (__bf16)f0[1]; h[2] = (__bf16)f0[2]; h[3] = (__bf16)f0[3];
    h[4] = (__bf16)f1[0]; h[5] = (__bf16)f1[1]; h[6] = (__bf16)f1[2]; h[7] = (__bf16)f1[3];
    *(bf16x8*)&Wt[(size_t)tg * 8] = h;
}

// ---------------- K1: fused GEMM + tanh + dot(v) -> scores (atomic partials) ----------------
// 4096 blocks = 1024 row-groups (64 rows) x 4 col-groups (256 cols).
// A chunk (64 rows x 256 K) staged fp32->bf16 in LDS (32 KB), 4 chunks over K=1024.
// B fragments read direct from pre-tiled Wt (L2-hot), 1-step prefetch. acc = 64 VGPRs.
__global__ __launch_bounds__(256, 3) void k_scores(const float* __restrict__ enc,
                                                   const float* __restrict__ decp,
                                                   const __bf16* __restrict__ Wt,
                                                   const float* __restrict__ v,
                                                   float* __restrict__ scores) {
    __shared__ __bf16 A_lds[64 * 256];   // 32 KB, fragment-major w/ (rr+ks)&15 swizzle
    __shared__ float red[4][64];

    const int tid = threadIdx.x;
    const int w = tid >> 6, lane = tid & 63;
    const int r = lane & 15, quad = lane >> 4;

    // XCD-swizzled decode: blocks sharing A-rows land on the same XCD, adjacent in time.
    const int bx = blockIdx.x;
    const int xs = bx & 7;
    const int q = bx >> 3;
    const int nt = q & 3;                  // col-group
    const int rg = (q >> 2) * 8 + xs;      // row-group 0..1023
    const int m0 = rg * 64;
    const int b = m0 >> 11;
    const int ngbase = nt * 16 + w * 4;    // Wt fragment group base for this wave

    float dp[4], vvv[4];
#pragma unroll
    for (int j = 0; j < 4; ++j) {
        int col = nt * 256 + w * 64 + j * 16 + r;
        dp[j]  = decp[b * H_ + col];
        vvv[j] = v[col];
    }

    f32x4 acc[4][4];
#pragma unroll
    for (int i = 0; i < 4; ++i)
#pragma unroll
        for (int j = 0; j < 4; ++j) {
            f32x4 z; z[0] = dp[j]; z[1] = dp[j]; z[2] = dp[j]; z[3] = dp[j];
            acc[i][j] = z;   // fold dec_p into accumulator init
        }

    // staging thread mapping (fixed across chunks)
    const int rg8 = tid >> 5;        // 0..7 -> rows rg8*8 .. +8
    const int tt  = tid & 31;        // k-octet within chunk
    const int ks_s = tt >> 2;        // k32 index within chunk
    const int lq  = tt & 3;

    bf16x8 b_cur[4];
#pragma unroll
    for (int j = 0; j < 4; ++j)
        b_cur[j] = *(const bf16x8*)&Wt[(((size_t)0 * 64 + ngbase + j) * 64 + lane) * 8];

#pragma unroll 1
    for (int kc = 0; kc < 4; ++kc) {
        // ---- stage A chunk kc: 64 rows x 256 k ----
        {
            const float* srow = &enc[(size_t)(m0 + rg8 * 8) * H_ + kc * 256 + tt * 8];
#pragma unroll
            for (int i = 0; i < 8; ++i) {
                const f32x4* s4 = (const f32x4*)(srow + (size_t)i * H_);
                f32x4 f0 = s4[0], f1 = s4[1];
                bf16x8 h;
                h[0] = (__bf16)f0[0]; h[1] = (__bf16)f0[1]; h[2] = (__bf16)f0[2]; h[3] = (__bf16)f0[3];
                h[4] = (__bf16)f1[0]; h[5] = (__bf16)f1[1]; h[6] = (__bf16)f1[2]; h[7] = (__bf16)f1[3];
                int row = rg8 * 8 + i;
                int mg = row >> 4, rr = row & 15;
                int cell = (ks_s * 4 + mg) * 64 + lq * 16 + ((rr + ks_s) & 15); // swizzled
                *(bf16x8*)&A_lds[cell * 8] = h;
            }
        }
        __syncthreads();

#pragma unroll
        for (int ks = 0; ks < 8; ++ks) {
            int kk = kc * 8 + ks;
            int kkn = (kk + 1) & 31;
            bf16x8 b_nxt[4];
#pragma unroll
            for (int j = 0; j < 4; ++j)
                b_nxt[j] = *(const bf16x8*)&Wt[(((size_t)kkn * 64 + ngbase + j) * 64 + lane) * 8];

            bf16x8 af[4];
            const int L = (lane & 48) | ((lane + ks) & 15);   // undo swizzle
#pragma unroll
            for (int i = 0; i < 4; ++i)
                af[i] = *(const bf16x8*)&A_lds[((ks * 4 + i) * 64 + L) * 8];

#pragma unroll
            for (int i = 0; i < 4; ++i)
#pragma unroll
                for (int j = 0; j < 4; ++j)
                    acc[i][j] = __builtin_amdgcn_mfma_f32_16x16x32_bf16(af[i], b_cur[j], acc[i][j], 0, 0, 0);

#pragma unroll
            for (int j = 0; j < 4; ++j) b_cur[j] = b_nxt[j];
        }
        __syncthreads();   // all waves done reading before restage
    }

    // ---- epilogue: partial score over this block's 256 cols ----
    float sp[4][4];
#pragma unroll
    for (int i = 0; i < 4; ++i)
#pragma unroll
        for (int g = 0; g < 4; ++g) sp[i][g] = 0.f;

#pragma unroll
    for (int i = 0; i < 4; ++i)
#pragma unroll
        for (int j = 0; j < 4; ++j)
#pragma unroll
            for (int g = 0; g < 4; ++g)
                sp[i][g] += tanh_fast(acc[i][j][g]) * vvv[j];

#pragma unroll
    for (int i = 0; i < 4; ++i)
#pragma unroll
        for (int g = 0; g < 4; ++g) {
            float s = sp[i][g];
            s += __shfl_xor(s, 1);
            s += __shfl_xor(s, 2);
            s += __shfl_xor(s, 4);
            s += __shfl_xor(s, 8);
            sp[i][g] = s;
        }

    if (r == 0) {
#pragma unroll
        for (int i = 0; i < 4; ++i)
#pragma unroll
            for (int g = 0; g < 4; ++g)
                red[w][i * 16 + quad * 4 + g] = sp[i][g];
    }
    __syncthreads();
    if (tid < 64) {
        float s = red[0][tid] + red[1][tid] + red[2][tid] + red[3][tid];
        atomicAdd(&scores[m0 + tid], s);
    }
}

// ---------------- K2: masked softmax over T per batch row ----------------
__global__ __launch_bounds__(256) void k_softmax(const float* __restrict__ scores,
                                                 const int* __restrict__ mask,
                                                 float* __restrict__ attn) {
    int b = blockIdx.x;
    int tid = threadIdx.x;
    int w = tid >> 6, lane = tid & 63;
    __shared__ float sm[2][4];
    float val[8];
    float mx = -3e38f;
#pragma unroll
    for (int ii = 0; ii < 8; ++ii) {
        int t = tid + ii * 256;
        float s = scores[b * T_ + t];
        s = (mask[b * T_ + t] == 0) ? -1e9f : s;
        val[ii] = s;
        mx = fmaxf(mx, s);
    }
#pragma unroll
    for (int m = 1; m <= 32; m <<= 1) mx = fmaxf(mx, __shfl_xor(mx, m));
    if (lane == 0) sm[0][w] = mx;
    __syncthreads();
    mx = fmaxf(fmaxf(sm[0][0], sm[0][1]), fmaxf(sm[0][2], sm[0][3]));
    float lsum = 0.f;
#pragma unroll
    for (int ii = 0; ii < 8; ++ii) {
        val[ii] = __expf(val[ii] - mx);
        lsum += val[ii];
    }
#pragma unroll
    for (int m = 1; m <= 32; m <<= 1) lsum += __shfl_xor(lsum, m);
    if (lane == 0) sm[1][w] = lsum;
    __syncthreads();
    float inv = 1.0f / (sm[1][0] + sm[1][1] + sm[1][2] + sm[1][3]);
#pragma unroll
    for (int ii = 0; ii < 8; ++ii)
        attn[b * T_ + tid + ii * 256] = val[ii] * inv;
}

// ---------------- K3: context[b,h] = sum_t attn[b,t] * enc[b,t,h] ----------------
__global__ __launch_bounds__(256) void k_context(const float* __restrict__ enc,
                                                 const float* __restrict__ attn,
                                                 float* __restrict__ ctx) {
    int bx = blockIdx.x;
    int b = bx >> 4;
    int sub = bx & 15;
    int hc = sub & 3;
    int tq = sub >> 2;
    int tid = threadIdx.x;
    int wv = tid >> 6, lane = tid & 63;
    int h4 = hc * 256 + lane * 4;
    int t0 = tq * 512 + wv * 128;
    f32x4 acc = {0.f, 0.f, 0.f, 0.f};
#pragma unroll 4
    for (int i = 0; i < 128; ++i) {
        int t = t0 + i;
        float a = attn[b * T_ + t];
        f32x4 e = *(const f32x4*)&enc[((size_t)(b * T_ + t)) * H_ + h4];
        acc += a * e;
    }
    float* out = &ctx[b * H_ + h4];
    atomicAdd(&out[0], acc[0]);
    atomicAdd(&out[1], acc[1]);
    atomicAdd(&out[2], acc[2]);
    atomicAdd(&out[3], acc[3]);
}

extern "C" void kernel_launch(void* const* d_in, const int* in_sizes, int n_in,
                              void* d_out, int out_size, void* d_ws, size_t ws_size,
                              hipStream_t stream) {
    (void)in_sizes; (void)n_in; (void)out_size; (void)ws_size;
    const float* dec  = (const float*)d_in[0];
    const float* enc  = (const float*)d_in[1];
    const int*   mask = (const int*)d_in[2];
    const float* We   = (const float*)d_in[3];
    const float* Wd   = (const float*)d_in[4];
    const float* v    = (const float*)d_in[5];

    float* out = (float*)d_out;                 // [0,32768) context ; [32768,98304) attn
    char* ws = (char*)d_ws;
    float*  decp   = (float*)ws;                        // 128 KB
    float*  scores = (float*)(ws + 131072);             // 256 KB
    __bf16* Wt     = (__bf16*)(ws + 131072 + 262144);   // 2 MB

    hipMemsetAsync(out, 0, (size_t)B_ * H_ * sizeof(float), stream);       // context accum
    hipMemsetAsync(scores, 0, (size_t)M_ * sizeof(float), stream);         // score partials

    k_decp   <<<512, 256, 0, stream>>>(dec, Wd, decp);
    k_wtile  <<<512, 256, 0, stream>>>(We, Wt);
    k_scores <<<4096, 256, 0, stream>>>(enc, decp, Wt, v, scores);
    k_softmax<<<32, 256, 0, stream>>>(scores, mask, out + B_ * H_);
    k_context<<<512, 256, 0, stream>>>(enc, out + B_ * H_, out);
}

// Round 3
// 588.534 us; speedup vs baseline: 2.0340x; 1.0120x over previous
//
#include <hip/hip_runtime.h>
#include <hip/hip_bf16.h>
#include <stdint.h>

#define B_ 32
#define T_ 2048
#define H_ 1024
#define M_ (B_*T_)

typedef __bf16 bf16x8 __attribute__((ext_vector_type(8)));
typedef float  f32x4  __attribute__((ext_vector_type(4)));
typedef float  f32x16 __attribute__((ext_vector_type(16)));

__device__ __forceinline__ float tanh_fast(float x) {
    float e = __expf(2.0f * x);
    return 1.0f - 2.0f / (e + 1.0f);
}

// ---------------- K0: fused prep ----------------
// blocks [0,512): tile W_enc fp32 -> bf16 fragment-major for 32x32x16 MFMA.
//   cell tg = (s*32 + c)*64 + lane ; holds W[o=c*32+(lane&31)][k=s*16+(lane>>5)*8 .. +8]
// blocks [512,1024): dec_p[b,o] fp32 matvec.
__global__ __launch_bounds__(256) void k_prep(const float* __restrict__ We,
                                              __bf16* __restrict__ Wt,
                                              const float* __restrict__ dec,
                                              const float* __restrict__ Wd,
                                              float* __restrict__ decp) {
    int bx = blockIdx.x;
    int tid = threadIdx.x;
    if (bx < 512) {
        int tg = bx * 256 + tid;             // 131072 cells
        int lane = tg & 63;
        int c = (tg >> 6) & 31;
        int s = tg >> 11;                    // 0..63
        int o = c * 32 + (lane & 31);
        int k = s * 16 + (lane >> 5) * 8;
        const f32x4* src = (const f32x4*)&We[(size_t)o * H_ + k];
        f32x4 f0 = src[0], f1 = src[1];
        bf16x8 h;
        h[0] = (__bf16)f0[0]; h[1] = (__bf16)f0[1]; h[2] = (__bf16)f0[2]; h[3] = (__bf16)f0[3];
        h[4] = (__bf16)f1[0]; h[5] = (__bf16)f1[1]; h[6] = (__bf16)f1[2]; h[7] = (__bf16)f1[3];
        *(bf16x8*)&Wt[(size_t)tg * 8] = h;
    } else {
        int bxd = bx - 512;
        int b = bxd & 31, oc = bxd >> 5;
        int o = oc * 64 + (tid >> 2);
        int kq = tid & 3;
        const f32x4* wr = (const f32x4*)&Wd[(size_t)o * H_ + kq * 256];
        const f32x4* dr = (const f32x4*)&dec[(size_t)b * H_ + kq * 256];
        f32x4 s4 = {0.f, 0.f, 0.f, 0.f};
#pragma unroll 8
        for (int i = 0; i < 64; ++i) s4 += wr[i] * dr[i];
        float s = s4[0] + s4[1] + s4[2] + s4[3];
        s += __shfl_xor(s, 1);
        s += __shfl_xor(s, 2);
        if (kq == 0) decp[b * H_ + o] = s;
    }
}

// ---------------- K1: fused GEMM(32x32x16) + tanh + dot(v) -> scores ----------------
// 4096 blocks = 1024 row-groups (64 rows) x 4 col-groups (256 cols), 4 waves.
// Wave w: cols w*64..+64 of the group = 2 col-tiles of 32. acc 2x2 f32x16 = 64 VGPR.
// A chunk (64 x 256) in LDS, XOR-swizzled: cell = row*32 + ((ko&24)|((ko^row)&7)).
__global__ __launch_bounds__(256, 4) void k_scores(const float* __restrict__ enc,
                                                   const float* __restrict__ decp,
                                                   const __bf16* __restrict__ Wt,
                                                   const float* __restrict__ v,
                                                   float* __restrict__ scores) {
    __shared__ __bf16 A_lds[64 * 32 * 8];   // 32 KB
    __shared__ float red[4][64];

    const int tid = threadIdx.x;
    const int w = tid >> 6, lane = tid & 63;
    const int l5 = lane & 31, q2 = lane >> 5;

    // XCD-swizzled block decode
    const int bx = blockIdx.x;
    const int xs = bx & 7;
    const int q = bx >> 3;
    const int nt = q & 3;                   // col-group (256 cols)
    const int rg = (q >> 2) * 8 + xs;       // row-group 0..1023
    const int m0 = rg * 64;
    const int b = m0 >> 11;
    const int cg0 = nt * 8 + w * 2;         // global 32-col tile index, ct=0

    float dp[2], vvv[2];
#pragma unroll
    for (int ct = 0; ct < 2; ++ct) {
        int col = (cg0 + ct) * 32 + l5;
        dp[ct]  = decp[b * H_ + col];
        vvv[ct] = v[col];
    }

    f32x16 acc[2][2];
#pragma unroll
    for (int rt = 0; rt < 2; ++rt)
#pragma unroll
        for (int ct = 0; ct < 2; ++ct)
#pragma unroll
            for (int g = 0; g < 16; ++g)
                acc[rt][ct][g] = dp[ct];    // dec_p folded into acc init

    // staging mapping
    const int ko_s = tid & 31;              // k-octet within chunk
    const int rbase = (tid >> 5) * 8;       // 8 rows per thread

    bf16x8 b_cur[2];
#pragma unroll
    for (int ct = 0; ct < 2; ++ct)
        b_cur[ct] = *(const bf16x8*)&Wt[(((size_t)0 * 32 + cg0 + ct) * 64 + lane) * 8];

#pragma unroll 1
    for (int kc = 0; kc < 4; ++kc) {
        // ---- stage A chunk: 64 rows x 256 k, fp32 -> bf16, swizzled ----
        {
            const float* sp0 = &enc[(size_t)(m0 + rbase) * H_ + kc * 256 + ko_s * 8];
#pragma unroll
            for (int i = 0; i < 8; ++i) {
                const f32x4* s4 = (const f32x4*)(sp0 + (size_t)i * H_);
                f32x4 f0 = s4[0], f1 = s4[1];
                bf16x8 h;
                h[0] = (__bf16)f0[0]; h[1] = (__bf16)f0[1]; h[2] = (__bf16)f0[2]; h[3] = (__bf16)f0[3];
                h[4] = (__bf16)f1[0]; h[5] = (__bf16)f1[1]; h[6] = (__bf16)f1[2]; h[7] = (__bf16)f1[3];
                int row = rbase + i;
                int cell = row * 32 + ((ko_s & 24) | ((ko_s ^ row) & 7));
                *(bf16x8*)&A_lds[cell * 8] = h;
            }
        }
        __syncthreads();

#pragma unroll
        for (int sl = 0; sl < 16; ++sl) {
            int s = kc * 16 + sl;
            int sn = (s + 1) & 63;
            bf16x8 b_nxt[2];
#pragma unroll
            for (int ct = 0; ct < 2; ++ct)
                b_nxt[ct] = *(const bf16x8*)&Wt[(((size_t)sn * 32 + cg0 + ct) * 64 + lane) * 8];

            bf16x8 af[2];
#pragma unroll
            for (int rt = 0; rt < 2; ++rt) {
                int row = rt * 32 + l5;
                int ko = sl * 2 + q2;
                int cell = row * 32 + ((ko & 24) | ((ko ^ row) & 7));
                af[rt] = *(const bf16x8*)&A_lds[cell * 8];
            }

            acc[0][0] = __builtin_amdgcn_mfma_f32_32x32x16_bf16(af[0], b_cur[0], acc[0][0], 0, 0, 0);
            acc[0][1] = __builtin_amdgcn_mfma_f32_32x32x16_bf16(af[0], b_cur[1], acc[0][1], 0, 0, 0);
            acc[1][0] = __builtin_amdgcn_mfma_f32_32x32x16_bf16(af[1], b_cur[0], acc[1][0], 0, 0, 0);
            acc[1][1] = __builtin_amdgcn_mfma_f32_32x32x16_bf16(af[1], b_cur[1], acc[1][1], 0, 0, 0);

            b_cur[0] = b_nxt[0];
            b_cur[1] = b_nxt[1];
        }
        __syncthreads();
    }

    // ---- epilogue: sp[rt][reg] = sum_ct tanh(acc)*v ; C-layout row=(reg&3)+8*(reg>>2)+4*q2 ----
    float sp[2][16];
#pragma unroll
    for (int rt = 0; rt < 2; ++rt)
#pragma unroll
        for (int g = 0; g < 16; ++g)
            sp[rt][g] = tanh_fast(acc[rt][0][g]) * vvv[0] + tanh_fast(acc[rt][1][g]) * vvv[1];

#pragma unroll
    for (int rt = 0; rt < 2; ++rt)
#pragma unroll
        for (int g = 0; g < 16; ++g) {
            float s = sp[rt][g];
            s += __shfl_xor(s, 1);
            s += __shfl_xor(s, 2);
            s += __shfl_xor(s, 4);
            s += __shfl_xor(s, 8);
            s += __shfl_xor(s, 16);
            sp[rt][g] = s;
        }

    if (l5 == 0) {
#pragma unroll
        for (int rt = 0; rt < 2; ++rt)
#pragma unroll
            for (int g = 0; g < 16; ++g) {
                int row = rt * 32 + (g & 3) + 8 * (g >> 2) + 4 * q2;
                red[w][row] = sp[rt][g];
            }
    }
    __syncthreads();
    if (tid < 64) {
        float s = red[0][tid] + red[1][tid] + red[2][tid] + red[3][tid];
        atomicAdd(&scores[m0 + tid], s);
    }
}

// ---------------- K2: masked softmax over T per batch row ----------------
__global__ __launch_bounds__(256) void k_softmax(const float* __restrict__ scores,
                                                 const int* __restrict__ mask,
                                                 float* __restrict__ attn) {
    int b = blockIdx.x;
    int tid = threadIdx.x;
    int w = tid >> 6, lane = tid & 63;
    __shared__ float sm[2][4];
    float val[8];
    float mx = -3e38f;
#pragma unroll
    for (int ii = 0; ii < 8; ++ii) {
        int t = tid + ii * 256;
        float s = scores[b * T_ + t];
        s = (mask[b * T_ + t] == 0) ? -1e9f : s;
        val[ii] = s;
        mx = fmaxf(mx, s);
    }
#pragma unroll
    for (int m = 1; m <= 32; m <<= 1) mx = fmaxf(mx, __shfl_xor(mx, m));
    if (lane == 0) sm[0][w] = mx;
    __syncthreads();
    mx = fmaxf(fmaxf(sm[0][0], sm[0][1]), fmaxf(sm[0][2], sm[0][3]));
    float lsum = 0.f;
#pragma unroll
    for (int ii = 0; ii < 8; ++ii) {
        val[ii] = __expf(val[ii] - mx);
        lsum += val[ii];
    }
#pragma unroll
    for (int m = 1; m <= 32; m <<= 1) lsum += __shfl_xor(lsum, m);
    if (lane == 0) sm[1][w] = lsum;
    __syncthreads();
    float inv = 1.0f / (sm[1][0] + sm[1][1] + sm[1][2] + sm[1][3]);
#pragma unroll
    for (int ii = 0; ii < 8; ++ii)
        attn[b * T_ + tid + ii * 256] = val[ii] * inv;
}

// ---------------- K3: context[b,h] = sum_t attn[b,t]*enc[b,t,h] (no atomics) ----------------
// 256 blocks = 32 b x 8 h-chunks(128). 512 threads = 8 waves, each wave 256 t's.
__global__ __launch_bounds__(512) void k_context(const float* __restrict__ enc,
                                                 const float* __restrict__ attn,
                                                 float* __restrict__ ctx) {
    __shared__ f32x4 cred[8][32];
    int bx = blockIdx.x;
    int b = bx >> 3, hc = bx & 7;
    int tid = threadIdx.x;
    int wv = tid >> 6, lane = tid & 63;
    int l5 = lane & 31, tq2 = lane >> 5;
    int h = hc * 128 + l5 * 4;
    const float* ap = &attn[b * T_ + wv * 256 + tq2];
    const float* ep = &enc[((size_t)b * T_ + wv * 256 + tq2) * H_ + h];
    f32x4 acc = {0.f, 0.f, 0.f, 0.f};
#pragma unroll 8
    for (int i = 0; i < 128; ++i) {
        float a = ap[2 * i];
        f32x4 e = *(const f32x4*)(ep + (size_t)2 * i * H_);
        acc += a * e;
    }
    // combine the two t-halves within the wave
#pragma unroll
    for (int c = 0; c < 4; ++c) acc[c] += __shfl_xor(acc[c], 32);
    if (tq2 == 0) cred[wv][l5] = acc;
    __syncthreads();
    if (tid < 32) {
        f32x4 r = cred[0][tid];
#pragma unroll
        for (int j = 1; j < 8; ++j) r += cred[j][tid];
        *(f32x4*)&ctx[b * H_ + hc * 128 + tid * 4] = r;
    }
}

extern "C" void kernel_launch(void* const* d_in, const int* in_sizes, int n_in,
                              void* d_out, int out_size, void* d_ws, size_t ws_size,
                              hipStream_t stream) {
    (void)in_sizes; (void)n_in; (void)out_size; (void)ws_size;
    const float* dec  = (const float*)d_in[0];
    const float* enc  = (const float*)d_in[1];
    const int*   mask = (const int*)d_in[2];
    const float* We   = (const float*)d_in[3];
    const float* Wd   = (const float*)d_in[4];
    const float* v    = (const float*)d_in[5];

    float* out = (float*)d_out;                 // [0,32768) context ; [32768,98304) attn
    char* ws = (char*)d_ws;
    float*  decp   = (float*)ws;                        // 128 KB
    float*  scores = (float*)(ws + 131072);             // 256 KB
    __bf16* Wt     = (__bf16*)(ws + 131072 + 262144);   // 2 MB

    hipMemsetAsync(scores, 0, (size_t)M_ * sizeof(float), stream);  // score partial accum

    k_prep   <<<1024, 256, 0, stream>>>(We, Wt, dec, Wd, decp);
    k_scores <<<4096, 256, 0, stream>>>(enc, decp, Wt, v, scores);
    k_softmax<<<32, 256, 0, stream>>>(scores, mask, out + B_ * H_);
    k_context<<<256, 512, 0, stream>>>(enc, out + B_ * H_, out);
}

// Round 4
// 582.134 us; speedup vs baseline: 2.0564x; 1.0110x over previous
//
#include <hip/hip_runtime.h>
#include <hip/hip_bf16.h>
#include <stdint.h>

#define B_ 32
#define T_ 2048
#define H_ 1024
#define M_ (B_*T_)

typedef __bf16 bf16x8 __attribute__((ext_vector_type(8)));
typedef float  f32x4  __attribute__((ext_vector_type(4)));
typedef float  f32x16 __attribute__((ext_vector_type(16)));

__device__ __forceinline__ float tanh_fast(float x) {
    float e = __expf(2.0f * x);
    return 1.0f - 2.0f / (e + 1.0f);
}

__device__ __forceinline__ bf16x8 cvt2(f32x4 f0, f32x4 f1) {
    bf16x8 h;
    h[0] = (__bf16)f0[0]; h[1] = (__bf16)f0[1]; h[2] = (__bf16)f0[2]; h[3] = (__bf16)f0[3];
    h[4] = (__bf16)f1[0]; h[5] = (__bf16)f1[1]; h[6] = (__bf16)f1[2]; h[7] = (__bf16)f1[3];
    return h;
}

// ---------------- K0: fused prep (W_enc -> bf16 fragment tiles ; dec_p matvec) ----------------
__global__ __launch_bounds__(256) void k_prep(const float* __restrict__ We,
                                              __bf16* __restrict__ Wt,
                                              const float* __restrict__ dec,
                                              const float* __restrict__ Wd,
                                              float* __restrict__ decp) {
    int bx = blockIdx.x;
    int tid = threadIdx.x;
    if (bx < 512) {
        int tg = bx * 256 + tid;             // 131072 cells
        int lane = tg & 63;
        int c = (tg >> 6) & 31;
        int s = tg >> 11;                    // 0..63
        int o = c * 32 + (lane & 31);
        int k = s * 16 + (lane >> 5) * 8;
        const f32x4* src = (const f32x4*)&We[(size_t)o * H_ + k];
        *(bf16x8*)&Wt[(size_t)tg * 8] = cvt2(src[0], src[1]);
    } else {
        int bxd = bx - 512;
        int b = bxd & 31, oc = bxd >> 5;
        int o = oc * 64 + (tid >> 2);
        int kq = tid & 3;
        const f32x4* wr = (const f32x4*)&Wd[(size_t)o * H_ + kq * 256];
        const f32x4* dr = (const f32x4*)&dec[(size_t)b * H_ + kq * 256];
        f32x4 s4 = {0.f, 0.f, 0.f, 0.f};
#pragma unroll 8
        for (int i = 0; i < 64; ++i) s4 += wr[i] * dr[i];
        float s = s4[0] + s4[1] + s4[2] + s4[3];
        s += __shfl_xor(s, 1);
        s += __shfl_xor(s, 2);
        if (kq == 0) decp[b * H_ + o] = s;
    }
}

// ---------------- K1: fused GEMM(32x32x16) + tanh + dot(v) -> score partials ----------------
// 4096 blocks = 1024 row-groups (64 rows) x 4 col-groups (256 cols), 4 waves.
// A: double-buffered LDS (2 x 32 KB), staging loads for chunk kc+1 held in regs across
// the MFMA loop of kc (latency overlapped). B: 4-deep register ring from L2-resident Wt.
// A ds_read: 2-deep ring. Partial scores stored per col-group (no atomics).
__global__ __launch_bounds__(256, 2) void k_scores(const float* __restrict__ enc,
                                                   const float* __restrict__ decp,
                                                   const __bf16* __restrict__ Wt,
                                                   const float* __restrict__ v,
                                                   float* __restrict__ scores_p) {
    __shared__ __bf16 A_lds[2][64 * 32 * 8];   // 2 x 32 KB
    __shared__ float red[4][64];

    const int tid = threadIdx.x;
    const int w = tid >> 6, lane = tid & 63;
    const int l5 = lane & 31, q2 = lane >> 5;

    // XCD-swizzled block decode
    const int bx = blockIdx.x;
    const int xs = bx & 7;
    const int q = bx >> 3;
    const int nt = q & 3;                   // col-group (256 cols)
    const int rg = (q >> 2) * 8 + xs;       // row-group 0..1023
    const int m0 = rg * 64;
    const int b = m0 >> 11;
    const int cg0 = nt * 8 + w * 2;         // global 32-col tile index

    float dp[2], vvv[2];
#pragma unroll
    for (int ct = 0; ct < 2; ++ct) {
        int col = (cg0 + ct) * 32 + l5;
        dp[ct]  = decp[b * H_ + col];
        vvv[ct] = v[col];
    }

    f32x16 acc[2][2];
#pragma unroll
    for (int rt = 0; rt < 2; ++rt)
#pragma unroll
        for (int ct = 0; ct < 2; ++ct)
#pragma unroll
            for (int g = 0; g < 16; ++g)
                acc[rt][ct][g] = dp[ct];

    // staging mapping: thread covers 8 rows x one k-octet
    const int ko_s = tid & 31;
    const int rbase = (tid >> 5) * 8;
    const float* sbase = &enc[(size_t)(m0 + rbase) * H_ + ko_s * 8];

    // ---- prologue: stage chunk 0 into buf 0 ----
    {
#pragma unroll
        for (int i = 0; i < 8; ++i) {
            const f32x4* s4 = (const f32x4*)(sbase + (size_t)i * H_);
            int row = rbase + i;
            int cell = row * 32 + ((ko_s & 24) | ((ko_s ^ row) & 7));
            *(bf16x8*)&A_lds[0][cell * 8] = cvt2(s4[0], s4[1]);
        }
    }
    __syncthreads();

    // ---- B ring prologue: slices 0..3 ----
    bf16x8 bb[4][2];
#pragma unroll
    for (int p = 0; p < 4; ++p)
#pragma unroll
        for (int ct = 0; ct < 2; ++ct)
            bb[p][ct] = *(const bf16x8*)&Wt[(((size_t)p * 32 + cg0 + ct) * 64 + lane) * 8];

#pragma unroll 1
    for (int kc = 0; kc < 4; ++kc) {
        const __bf16* buf = A_lds[kc & 1];

        // issue global loads for chunk kc+1; held in regs across the MFMA loop
        f32x4 sr[8][2];
        if (kc < 3) {
            const float* sp0 = sbase + (size_t)(kc + 1) * 256;
#pragma unroll
            for (int i = 0; i < 8; ++i) {
                const f32x4* s4 = (const f32x4*)(sp0 + (size_t)i * H_);
                sr[i][0] = s4[0];
                sr[i][1] = s4[1];
            }
        }

        // A ring prologue: sl = 0, 1
        bf16x8 af[2][2];
#pragma unroll
        for (int p = 0; p < 2; ++p)
#pragma unroll
            for (int rt = 0; rt < 2; ++rt) {
                int row = rt * 32 + l5;
                int ko = p * 2 + q2;
                int cell = row * 32 + ((ko & 24) | ((ko ^ row) & 7));
                af[p][rt] = *(const bf16x8*)&buf[cell * 8];
            }

#pragma unroll
        for (int sl = 0; sl < 16; ++sl) {
            const int s = kc * 16 + sl;
            bf16x8 a0 = af[sl & 1][0], a1 = af[sl & 1][1];
            bf16x8 w0 = bb[s & 3][0],  w1 = bb[s & 3][1];

            // prefetch B slice s+4 into the slot just freed
            {
                int sn = (s + 4) & 63;
#pragma unroll
                for (int ct = 0; ct < 2; ++ct)
                    bb[s & 3][ct] = *(const bf16x8*)&Wt[(((size_t)sn * 32 + cg0 + ct) * 64 + lane) * 8];
            }
            // prefetch A slice sl+2 (wraps harmlessly at chunk end)
            {
                int sl2 = (sl + 2) & 15;
#pragma unroll
                for (int rt = 0; rt < 2; ++rt) {
                    int row = rt * 32 + l5;
                    int ko = sl2 * 2 + q2;
                    int cell = row * 32 + ((ko & 24) | ((ko ^ row) & 7));
                    af[sl & 1][rt] = *(const bf16x8*)&buf[cell * 8];
                }
            }

            acc[0][0] = __builtin_amdgcn_mfma_f32_32x32x16_bf16(a0, w0, acc[0][0], 0, 0, 0);
            acc[0][1] = __builtin_amdgcn_mfma_f32_32x32x16_bf16(a0, w1, acc[0][1], 0, 0, 0);
            acc[1][0] = __builtin_amdgcn_mfma_f32_32x32x16_bf16(a1, w0, acc[1][0], 0, 0, 0);
            acc[1][1] = __builtin_amdgcn_mfma_f32_32x32x16_bf16(a1, w1, acc[1][1], 0, 0, 0);
        }

        // write staged chunk kc+1 into the other buffer
        if (kc < 3) {
            __bf16* dst = A_lds[(kc + 1) & 1];
#pragma unroll
            for (int i = 0; i < 8; ++i) {
                int row = rbase + i;
                int cell = row * 32 + ((ko_s & 24) | ((ko_s ^ row) & 7));
                *(bf16x8*)&dst[cell * 8] = cvt2(sr[i][0], sr[i][1]);
            }
        }
        __syncthreads();
    }

    // ---- epilogue ----
    float sp[2][16];
#pragma unroll
    for (int rt = 0; rt < 2; ++rt)
#pragma unroll
        for (int g = 0; g < 16; ++g)
            sp[rt][g] = tanh_fast(acc[rt][0][g]) * vvv[0] + tanh_fast(acc[rt][1][g]) * vvv[1];

#pragma unroll
    for (int rt = 0; rt < 2; ++rt)
#pragma unroll
        for (int g = 0; g < 16; ++g) {
            float s = sp[rt][g];
            s += __shfl_xor(s, 1);
            s += __shfl_xor(s, 2);
            s += __shfl_xor(s, 4);
            s += __shfl_xor(s, 8);
            s += __shfl_xor(s, 16);
            sp[rt][g] = s;
        }

    if (l5 == 0) {
#pragma unroll
        for (int rt = 0; rt < 2; ++rt)
#pragma unroll
            for (int g = 0; g < 16; ++g) {
                int row = rt * 32 + (g & 3) + 8 * (g >> 2) + 4 * q2;
                red[w][row] = sp[rt][g];
            }
    }
    __syncthreads();
    if (tid < 64) {
        float s = red[0][tid] + red[1][tid] + red[2][tid] + red[3][tid];
        scores_p[nt * M_ + m0 + tid] = s;   // per-col-group partial, no atomics
    }
}

// ---------------- K2: sum partials + masked softmax ----------------
__global__ __launch_bounds__(256) void k_softmax(const float* __restrict__ scores_p,
                                                 const int* __restrict__ mask,
                                                 float* __restrict__ attn) {
    int b = blockIdx.x;
    int tid = threadIdx.x;
    int w = tid >> 6, lane = tid & 63;
    __shared__ float sm[2][4];
    float val[8];
    float mx = -3e38f;
#pragma unroll
    for (int ii = 0; ii < 8; ++ii) {
        int idx = b * T_ + tid + ii * 256;
        float s = scores_p[idx] + scores_p[M_ + idx] + scores_p[2 * M_ + idx] + scores_p[3 * M_ + idx];
        s = (mask[idx] == 0) ? -1e9f : s;
        val[ii] = s;
        mx = fmaxf(mx, s);
    }
#pragma unroll
    for (int m = 1; m <= 32; m <<= 1) mx = fmaxf(mx, __shfl_xor(mx, m));
    if (lane == 0) sm[0][w] = mx;
    __syncthreads();
    mx = fmaxf(fmaxf(sm[0][0], sm[0][1]), fmaxf(sm[0][2], sm[0][3]));
    float lsum = 0.f;
#pragma unroll
    for (int ii = 0; ii < 8; ++ii) {
        val[ii] = __expf(val[ii] - mx);
        lsum += val[ii];
    }
#pragma unroll
    for (int m = 1; m <= 32; m <<= 1) lsum += __shfl_xor(lsum, m);
    if (lane == 0) sm[1][w] = lsum;
    __syncthreads();
    float inv = 1.0f / (sm[1][0] + sm[1][1] + sm[1][2] + sm[1][3]);
#pragma unroll
    for (int ii = 0; ii < 8; ++ii)
        attn[b * T_ + tid + ii * 256] = val[ii] * inv;
}

// ---------------- K3: context[b,h] = sum_t attn[b,t]*enc[b,t,h] (no atomics) ----------------
__global__ __launch_bounds__(512) void k_context(const float* __restrict__ enc,
                                                 const float* __restrict__ attn,
                                                 float* __restrict__ ctx) {
    __shared__ f32x4 cred[8][32];
    int bx = blockIdx.x;
    int b = bx >> 3, hc = bx & 7;
    int tid = threadIdx.x;
    int wv = tid >> 6, lane = tid & 63;
    int l5 = lane & 31, tq2 = lane >> 5;
    int h = hc * 128 + l5 * 4;
    const float* ap = &attn[b * T_ + wv * 256 + tq2];
    const float* ep = &enc[((size_t)b * T_ + wv * 256 + tq2) * H_ + h];
    f32x4 acc = {0.f, 0.f, 0.f, 0.f};
#pragma unroll 8
    for (int i = 0; i < 128; ++i) {
        float a = ap[2 * i];
        f32x4 e = *(const f32x4*)(ep + (size_t)2 * i * H_);
        acc += a * e;
    }
#pragma unroll
    for (int c = 0; c < 4; ++c) acc[c] += __shfl_xor(acc[c], 32);
    if (tq2 == 0) cred[wv][l5] = acc;
    __syncthreads();
    if (tid < 32) {
        f32x4 r = cred[0][tid];
#pragma unroll
        for (int j = 1; j < 8; ++j) r += cred[j][tid];
        *(f32x4*)&ctx[b * H_ + hc * 128 + tid * 4] = r;
    }
}

extern "C" void kernel_launch(void* const* d_in, const int* in_sizes, int n_in,
                              void* d_out, int out_size, void* d_ws, size_t ws_size,
                              hipStream_t stream) {
    (void)in_sizes; (void)n_in; (void)out_size; (void)ws_size;
    const float* dec  = (const float*)d_in[0];
    const float* enc  = (const float*)d_in[1];
    const int*   mask = (const int*)d_in[2];
    const float* We   = (const float*)d_in[3];
    const float* Wd   = (const float*)d_in[4];
    const float* v    = (const float*)d_in[5];

    float* out = (float*)d_out;                 // [0,32768) context ; [32768,98304) attn
    char* ws = (char*)d_ws;
    float*  decp     = (float*)ws;                          // 128 KB
    float*  scores_p = (float*)(ws + 131072);               // 4 x 256 KB = 1 MB
    __bf16* Wt       = (__bf16*)(ws + 131072 + 1048576);    // 2 MB

    k_prep   <<<1024, 256, 0, stream>>>(We, Wt, dec, Wd, decp);
    k_scores <<<4096, 256, 0, stream>>>(enc, decp, Wt, v, scores_p);
    k_softmax<<<32, 256, 0, stream>>>(scores_p, mask, out + B_ * H_);
    k_context<<<256, 512, 0, stream>>>(enc, out + B_ * H_, out);
}